// Round 1
// baseline (210.236 us; speedup 1.0000x reference)
//
#include <hip/hip_runtime.h>

#define BB    4096
#define NNUM  64
#define NCAT  64
#define CARD  100
#define DD    512
#define FF    128

__global__ __launch_bounds__(128) void rtdl_fused(
    const float* __restrict__ x_num,       // (B,64)
    const int*   __restrict__ x_cat,       // (B,64)
    const float* __restrict__ mask_num,    // (B,128)
    const float* __restrict__ mask_cat,    // (B,128)
    const int*   __restrict__ pred_idx_num,// (B)
    const int*   __restrict__ pred_idx_cat,// (B)
    const float* __restrict__ w_num,       // (64,512)
    const float* __restrict__ b_num,       // (64,512)
    const float* __restrict__ emb_cat,     // (6400,512)
    const float* __restrict__ b_cat,       // (64,512)
    const float* __restrict__ dec_num_W,   // (64,512)
    const float* __restrict__ dec_num_b,   // (64)
    const float* __restrict__ dec_cat_W,   // (64,100,512)
    const float* __restrict__ dec_cat_b,   // (64,100)
    float* __restrict__ out)               // [4096 | 4096*100]
{
    const int b   = blockIdx.x;
    const int tid = threadIdx.x;

    __shared__ float s_mn[FF];
    __shared__ float s_mc[FF];
    __shared__ float s_xn[NNUM];
    __shared__ int   s_xc[NCAT];
    __shared__ float s_pn[DD];
    __shared__ float s_pc[DD];

    // ---- stage per-row scalars into LDS ----
    s_mn[tid] = mask_num[b * FF + tid];
    s_mc[tid] = mask_cat[b * FF + tid];
    if (tid < NNUM) {
        s_xn[tid] = x_num[b * NNUM + tid];
        s_xc[tid] = x_cat[b * NCAT + tid];
    }
    __syncthreads();

    // mask sums (broadcast LDS reads, every thread computes — cheap)
    float sn = 0.f, sc = 0.f;
    #pragma unroll 8
    for (int f = 0; f < FF; ++f) { sn += s_mn[f]; sc += s_mc[f]; }
    const float inv_n = 1.f / sn;
    const float inv_c = 1.f / sc;

    // ---- phase 1: tokenize + dual masked pooling ----
    const int d4 = tid * 4;
    float anx = 0.f, any_ = 0.f, anz = 0.f, anw = 0.f;   // pooled_num acc
    float acx = 0.f, acy = 0.f, acz = 0.f, acw = 0.f;    // pooled_cat acc

    // numeric tokens f = 0..63
    for (int f = 0; f < NNUM; ++f) {
        const float mn = s_mn[f];
        const float mc = s_mc[f];
        if (mn == 0.f && mc == 0.f) continue;            // block-uniform skip
        const float x = s_xn[f];
        const float4 w  = *(const float4*)(w_num + f * DD + d4);
        const float4 bb = *(const float4*)(b_num + f * DD + d4);
        const float tx = fmaf(x, w.x, bb.x);
        const float ty = fmaf(x, w.y, bb.y);
        const float tz = fmaf(x, w.z, bb.z);
        const float tw = fmaf(x, w.w, bb.w);
        anx = fmaf(mn, tx, anx); any_ = fmaf(mn, ty, any_);
        anz = fmaf(mn, tz, anz); anw  = fmaf(mn, tw, anw);
        acx = fmaf(mc, tx, acx); acy  = fmaf(mc, ty, acy);
        acz = fmaf(mc, tz, acz); acw  = fmaf(mc, tw, acw);
    }
    // categorical tokens f = 0..63 (token index 64+f)
    for (int f = 0; f < NCAT; ++f) {
        const float mn = s_mn[NNUM + f];
        const float mc = s_mc[NNUM + f];
        if (mn == 0.f && mc == 0.f) continue;            // block-uniform skip
        const int row = s_xc[f] + f * CARD;              // shared-table offset
        const float4 e  = *(const float4*)(emb_cat + row * DD + d4);
        const float4 bc = *(const float4*)(b_cat + f * DD + d4);
        const float tx = e.x + bc.x;
        const float ty = e.y + bc.y;
        const float tz = e.z + bc.z;
        const float tw = e.w + bc.w;
        anx = fmaf(mn, tx, anx); any_ = fmaf(mn, ty, any_);
        anz = fmaf(mn, tz, anz); anw  = fmaf(mn, tw, anw);
        acx = fmaf(mc, tx, acx); acy  = fmaf(mc, ty, acy);
        acz = fmaf(mc, tz, acz); acw  = fmaf(mc, tw, acw);
    }

    s_pn[d4 + 0] = anx * inv_n; s_pn[d4 + 1] = any_ * inv_n;
    s_pn[d4 + 2] = anz * inv_n; s_pn[d4 + 3] = anw  * inv_n;
    s_pc[d4 + 0] = acx * inv_c; s_pc[d4 + 1] = acy  * inv_c;
    s_pc[d4 + 2] = acz * inv_c; s_pc[d4 + 3] = acw  * inv_c;
    __syncthreads();

    const int wave = tid >> 6;
    const int lane = tid & 63;

    // register-cache the pooled_cat slice this lane will reuse for all classes
    float pc[8];
    #pragma unroll
    for (int k = 0; k < 8; ++k) pc[k] = s_pc[lane * 8 + k];

    // ---- phase 2: numeric head (wave 0 only) ----
    if (wave == 0) {
        const int idx = pred_idx_num[b];
        const float* wv = dec_num_W + idx * DD + lane * 8;
        float v = 0.f;
        #pragma unroll
        for (int k = 0; k < 8; ++k) v = fmaf(s_pn[lane * 8 + k], wv[k], v);
        #pragma unroll
        for (int off = 32; off > 0; off >>= 1) v += __shfl_down(v, off);
        if (lane == 0) out[b] = v + dec_num_b[idx];
    }

    // ---- phase 3: categorical head, 100 classes split across 2 waves ----
    const int e = pred_idx_cat[b] - NNUM;
    const float* baseW = dec_cat_W + (size_t)e * CARD * DD;
    const float* baseb = dec_cat_b + e * CARD;
    float* outc = out + BB + (size_t)b * CARD;

    for (int c = wave; c < CARD; c += 2) {
        const float* wv = baseW + c * DD + lane * 8;
        float v = 0.f;
        #pragma unroll
        for (int k = 0; k < 8; ++k) v = fmaf(pc[k], wv[k], v);
        #pragma unroll
        for (int off = 32; off > 0; off >>= 1) v += __shfl_down(v, off);
        if (lane == 0) outc[c] = v + baseb[c];
    }
}

extern "C" void kernel_launch(void* const* d_in, const int* in_sizes, int n_in,
                              void* d_out, int out_size, void* d_ws, size_t ws_size,
                              hipStream_t stream) {
    const float* x_num        = (const float*)d_in[0];
    const int*   x_cat        = (const int*)  d_in[1];
    const float* mask_num     = (const float*)d_in[2];
    const float* mask_cat     = (const float*)d_in[3];
    const int*   pred_idx_num = (const int*)  d_in[4];
    const int*   pred_idx_cat = (const int*)  d_in[5];
    const float* w_num        = (const float*)d_in[6];
    const float* b_num        = (const float*)d_in[7];
    const float* emb_cat      = (const float*)d_in[8];
    const float* b_cat        = (const float*)d_in[9];
    const float* dec_num_W    = (const float*)d_in[10];
    const float* dec_num_b    = (const float*)d_in[11];
    const float* dec_cat_W    = (const float*)d_in[12];
    const float* dec_cat_b    = (const float*)d_in[13];
    float* out = (float*)d_out;

    rtdl_fused<<<BB, 128, 0, stream>>>(
        x_num, x_cat, mask_num, mask_cat, pred_idx_num, pred_idx_cat,
        w_num, b_num, emb_cat, b_cat, dec_num_W, dec_num_b,
        dec_cat_W, dec_cat_b, out);
}